// Round 6
// baseline (707.717 us; speedup 1.0000x reference)
//
#include <hip/hip_runtime.h>
#include <math.h>

// Problem constants (from reference)
#define N_    128
#define T_    1000
#define NS_   10
#define NO_   10
#define HID_  64
#define G3_   192
#define DENSE_ 32

typedef float v2f __attribute__((ext_vector_type(2)));
typedef float v4f __attribute__((ext_vector_type(4)));

// Barrier that waits only on LDS ops (global h_out stores are consumed by a
// later dispatch, never by another wave in-kernel -> no vmcnt drain).
#define LDS_BARRIER() asm volatile("s_waitcnt lgkmcnt(0)\n\ts_barrier" ::: "memory")

// Opaque def: blocks the register allocator's remat-reload heuristic
// (value's def becomes the asm, not a re-executable load).
#define KEEP(a) asm("" : "+v"(a))

__device__ __forceinline__ float fast_sigmoid(float x) {
    return __builtin_amdgcn_rcpf(1.f + __expf(-x));   // NaN-safe
}
__device__ __forceinline__ float fast_tanh(float x) {
    float e = __expf(2.f * x);
    return 1.f - 2.f * __builtin_amdgcn_rcpf(e + 1.f); // NaN-safe
}

// ---------------------------------------------------------------------------
// Phase 0: precompute A = H^T inv(C_w) (NS x NO), M = A H (NS x NS)
// ---------------------------------------------------------------------------
__global__ void setup_consts(const float* __restrict__ H,
                             const float* __restrict__ C_w,
                             float* __restrict__ A,   // (NS,NO)
                             float* __restrict__ M)   // (NS,NS)
{
    if (threadIdx.x != 0 || blockIdx.x != 0) return;
    float W[NO_][2 * NO_];
    for (int i = 0; i < NO_; ++i) {
        for (int j = 0; j < NO_; ++j) {
            W[i][j] = C_w[i * NO_ + j];
            W[i][NO_ + j] = (i == j) ? 1.f : 0.f;
        }
    }
    for (int p = 0; p < NO_; ++p) {
        float ip = 1.f / W[p][p];
        for (int j = 0; j < 2 * NO_; ++j) W[p][j] *= ip;
        for (int i = 0; i < NO_; ++i) {
            if (i == p) continue;
            float f = W[i][p];
            for (int j = 0; j < 2 * NO_; ++j) W[i][j] -= f * W[p][j];
        }
    }
    float Aloc[NS_][NO_];
    for (int s = 0; s < NS_; ++s) {
        for (int o = 0; o < NO_; ++o) {
            float acc = 0.f;
            for (int p = 0; p < NO_; ++p) acc += H[p * NS_ + s] * W[p][NO_ + o];
            Aloc[s][o] = acc;
            A[s * NO_ + o] = acc;
        }
    }
    for (int s = 0; s < NS_; ++s) {
        for (int q = 0; q < NS_; ++q) {
            float acc = 0.f;
            for (int o = 0; o < NO_; ++o) acc += Aloc[s][o] * H[o * NS_ + q];
            M[s * NS_ + q] = acc;
        }
    }
}

// ---------------------------------------------------------------------------
// Phase 1: GRU scan. 3 waves per sample = gates r/z/n; lane owns one gate row.
// Weights pinned register-resident (~74 regs; __launch_bounds__(192,1) gives
// the 512-VGPR budget so the allocator has no reason to remat-reload them
// from cache every step — the r2..r5 hidden cost). Per step:
//   - own-gate dot from PRIVATE h copy in LDS (same-wave in-order, no barrier)
//   - publish gate value(s) into stride-4B scalar arrays (conflict-free)
//   - ONE LDS-only barrier
//   - redundant combine on every wave: tanh + h update -> write own h copy;
//     wave 0 stores h_out (fire-and-forget)
// ---------------------------------------------------------------------------
__global__ __launch_bounds__(G3_, 1) void gru_kernel(
    const float* __restrict__ Y,     // (N,T,NO)
    const float* __restrict__ W_ih,  // (192,10)
    const float* __restrict__ W_hh,  // (192,64)
    const float* __restrict__ b_ih,
    const float* __restrict__ b_hh,
    float* __restrict__ h_out)       // (N*T,64)
{
    const int n = blockIdx.x;
    const int g = threadIdx.x >> 6;      // 0=r, 1=z, 2=n (wave-uniform)
    const int j = threadIdx.x & 63;
    const int row = threadIdx.x;         // gate row in [0,192)

    // --- weights for this gate row ---
    v2f whh[32];
    {
        const v4f* wp = (const v4f*)(W_hh + (size_t)row * HID_);
#pragma unroll
        for (int k = 0; k < 16; ++k) {
            v4f t = wp[k];
            whh[2 * k]     = __builtin_shufflevector(t, t, 0, 1);
            whh[2 * k + 1] = __builtin_shufflevector(t, t, 2, 3);
        }
    }
    v2f wih[5];
    {
        const v2f* p = (const v2f*)(W_ih + (size_t)row * NO_);
#pragma unroll
        for (int i = 0; i < 5; ++i) wih[i] = p[i];
    }
    // Pin register-resident: opaque defs can't be rematerialized as reloads.
#pragma unroll
    for (int k = 0; k < 32; ++k) KEEP(whh[k]);
#pragma unroll
    for (int i = 0; i < 5; ++i) KEEP(wih[i]);

    const float bi = b_ih[row];
    const float bh = b_hh[row];
    // r,z: bias folds into one accumulator; n: keep x/h parts separate
    const float bx = (g == 2) ? bi : (bi + bh);
    const float bhp = (g == 2) ? bh : 0.f;

    __shared__ __align__(16) float h_copy[3][HID_];   // private per-wave h
    // gate exchange, double-buffered, stride-4B scalar arrays (conflict-free)
    __shared__ float r_a[2][HID_], z_a[2][HID_], xn_a[2][HID_], hn_a[2][HID_];

    h_copy[g][j] = 0.f;    // own copy: same-wave in-order vs later reads
    float h_own = 0.f;

    const float* Yn = Y + (size_t)n * T_ * NO_;
    float* hout = h_out + (size_t)n * T_ * HID_ + j;

    // prefetch y[0] (uniform broadcast, 40B)
    v2f y[5];
    {
        const v2f* yp = (const v2f*)Yn;
#pragma unroll
        for (int i = 0; i < 5; ++i) y[i] = yp[i];
    }

    for (int t = 0; t < T_; ++t) {
        const int p = t & 1;

        // x-projection (registers)
        v2f ax = {bx, 0.f};
#pragma unroll
        for (int i = 0; i < 5; ++i) ax += wih[i] * y[i];

        // h-projection: 16 uniform b128 broadcast reads of own h copy
        v2f ah0 = {bhp, 0.f}, ah1 = {0.f, 0.f};
        const v4f* h4p = (const v4f*)h_copy[g];
#pragma unroll
        for (int k = 0; k < 16; ++k) {
            v4f h4 = h4p[k];
            ah0 += whh[2 * k]     * __builtin_shufflevector(h4, h4, 0, 1);
            ah1 += whh[2 * k + 1] * __builtin_shufflevector(h4, h4, 2, 3);
        }

        // prefetch y[t+1]
        {
            const int tn = (t + 1 < T_) ? t + 1 : t;
            const v2f* yp = (const v2f*)(Yn + tn * NO_);
#pragma unroll
            for (int i = 0; i < 5; ++i) y[i] = yp[i];
        }

        const float xs = ax[0] + ax[1];
        v2f ahv = ah0 + ah1;
        const float hs = ahv[0] + ahv[1];

        if (g == 0)      r_a[p][j] = fast_sigmoid(xs + hs);
        else if (g == 1) z_a[p][j] = fast_sigmoid(xs + hs);
        else {           // n-gate: publish x-part and h-part (r applied later)
            xn_a[p][j] = xs;
            hn_a[p][j] = hs;
        }
        LDS_BARRIER();

        // redundant combine on every wave (no second barrier)
        const float r  = r_a[p][j];
        const float z  = z_a[p][j];
        const float nn = fast_tanh(xn_a[p][j] + r * hn_a[p][j]);
        const float h_new = nn + z * (h_own - nn);
        h_own = h_new;
        h_copy[g][j] = h_new;               // own copy only
        if (g == 0) hout[t * HID_] = h_new; // fire-and-forget
    }
}

// ---------------------------------------------------------------------------
// Phase 2a: init output with the constant term 0.5*NS*T*log(2*pi)
// ---------------------------------------------------------------------------
__global__ void init_out(float* __restrict__ out)
{
    if (threadIdx.x == 0 && blockIdx.x == 0) {
        out[0] = 0.5f * (float)NS_ * (float)T_ * logf(2.f * 3.14159265358979323846f);
    }
}

// ---------------------------------------------------------------------------
// Phase 2b: per-(n,t) dense head + information-form Kalman + log-pdf terms.
// ---------------------------------------------------------------------------
__global__ __launch_bounds__(256) void post_kernel(
    const float* __restrict__ h_out,  // (N*T,64)
    const float* __restrict__ Y,      // (N,T,NO)
    const float* __restrict__ X,      // (N,T,NS)
    const float* __restrict__ W_fc, const float* __restrict__ b_fc,
    const float* __restrict__ W_mean, const float* __restrict__ b_mean,
    const float* __restrict__ W_vars, const float* __restrict__ b_vars,
    const float* __restrict__ Ac,     // (NS,NO)
    const float* __restrict__ Mc,     // (NS,NS)
    float* __restrict__ out)
{
    __shared__ float sWfc[DENSE_][HID_];
    __shared__ float sWm[NS_][DENSE_];
    __shared__ float sWv[NS_][DENSE_];
    __shared__ float sA[NS_][NO_];
    __shared__ float sM[NS_][NS_];
    __shared__ float sbfc[DENSE_], sbm[NS_], sbv[NS_];
    __shared__ float wsum[4];

    for (int i = threadIdx.x; i < DENSE_ * HID_; i += blockDim.x)
        sWfc[i / HID_][i % HID_] = W_fc[i];
    for (int i = threadIdx.x; i < NS_ * DENSE_; i += blockDim.x) {
        sWm[i / DENSE_][i % DENSE_] = W_mean[i];
        sWv[i / DENSE_][i % DENSE_] = W_vars[i];
    }
    for (int i = threadIdx.x; i < NS_ * NO_; i += blockDim.x) sA[i / NO_][i % NO_] = Ac[i];
    for (int i = threadIdx.x; i < NS_ * NS_; i += blockDim.x) sM[i / NS_][i % NS_] = Mc[i];
    if (threadIdx.x < DENSE_) sbfc[threadIdx.x] = b_fc[threadIdx.x];
    if (threadIdx.x < NS_) { sbm[threadIdx.x] = b_mean[threadIdx.x]; sbv[threadIdx.x] = b_vars[threadIdx.x]; }
    __syncthreads();

    const int task = blockIdx.x * blockDim.x + threadIdx.x;
    float contrib = 0.f;
    if (task < N_ * T_) {
        float y[DENSE_];
#pragma unroll
        for (int d = 0; d < DENSE_; ++d) y[d] = sbfc[d];
        const float* hp = h_out + (size_t)task * HID_;
#pragma unroll
        for (int k = 0; k < HID_; k += 4) {
            float4 h4 = *(const float4*)(hp + k);
#pragma unroll
            for (int d = 0; d < DENSE_; ++d) {
                y[d] += sWfc[d][k + 0] * h4.x + sWfc[d][k + 1] * h4.y +
                        sWfc[d][k + 2] * h4.z + sWfc[d][k + 3] * h4.w;
            }
        }
#pragma unroll
        for (int d = 0; d < DENSE_; ++d) y[d] = fmaxf(y[d], 0.f);

        float mu[NS_], vinv[NS_];
#pragma unroll
        for (int s = 0; s < NS_; ++s) {
            float am = sbm[s], av = sbv[s];
#pragma unroll
            for (int d = 0; d < DENSE_; ++d) { am += sWm[s][d] * y[d]; av += sWv[s][d] * y[d]; }
            mu[s] = am;
            float sp = (av > 20.f) ? av : log1pf(__expf(av));  // softplus
            vinv[s] = 1.f / sp;
        }

        const float* yo = Y + (size_t)task * NO_;
        const float* xo = X + (size_t)task * NS_;
        float b[NS_];
#pragma unroll
        for (int s = 0; s < NS_; ++s) {
            float acc = vinv[s] * mu[s];
#pragma unroll
            for (int o = 0; o < NO_; ++o) acc += sA[s][o] * yo[o];
            b[s] = acc;
        }

        // L_inv = M + diag(v^-1), Cholesky
        float L[NS_][NS_];
#pragma unroll
        for (int i = 0; i < NS_; ++i)
#pragma unroll
            for (int jj = 0; jj <= i; ++jj)
                L[i][jj] = sM[i][jj] + ((i == jj) ? vinv[i] : 0.f);
        float ld = 0.f;
        float dinv[NS_];
#pragma unroll
        for (int jj = 0; jj < NS_; ++jj) {
            float s = L[jj][jj];
#pragma unroll
            for (int k = 0; k < jj; ++k) s -= L[jj][k] * L[jj][k];
            float d = sqrtf(s);
            ld += __logf(d);
            float di = 1.f / d;
            dinv[jj] = di;
            L[jj][jj] = d;
#pragma unroll
            for (int i = jj + 1; i < NS_; ++i) {
                float t2 = L[i][jj];
#pragma unroll
                for (int k = 0; k < jj; ++k) t2 -= L[i][k] * L[jj][k];
                L[i][jj] = t2 * di;
            }
        }
        ld *= 2.f;

        float w[NS_];
#pragma unroll
        for (int i = 0; i < NS_; ++i) {
            float s = b[i];
#pragma unroll
            for (int k = 0; k < i; ++k) s -= L[i][k] * w[k];
            w[i] = s * dinv[i];
        }
        float mpost[NS_];
#pragma unroll
        for (int ii = NS_ - 1; ii >= 0; --ii) {
            float s = w[ii];
#pragma unroll
            for (int k = ii + 1; k < NS_; ++k) s -= L[k][ii] * mpost[k];
            mpost[ii] = s * dinv[ii];
        }

        float diff[NS_];
#pragma unroll
        for (int s = 0; s < NS_; ++s) diff[s] = xo[s] - mpost[s];
        float quad = 0.f;
#pragma unroll
        for (int jj = 0; jj < NS_; ++jj) {
            float u = 0.f;
#pragma unroll
            for (int i = jj; i < NS_; ++i) u += L[i][jj] * diff[i];
            quad += u * u;
        }

        contrib = 0.5f * (ld - quad) * (1.0f / (float)N_);
    }

#pragma unroll
    for (int off = 32; off; off >>= 1) contrib += __shfl_down(contrib, off);
    const int wid = threadIdx.x >> 6;
    if ((threadIdx.x & 63) == 0) wsum[wid] = contrib;
    __syncthreads();
    if (threadIdx.x == 0) {
        float s = 0.f;
#pragma unroll
        for (int i = 0; i < 4; ++i) s += wsum[i];
        atomicAdd(out, s);
    }
}

// ---------------------------------------------------------------------------
extern "C" void kernel_launch(void* const* d_in, const int* in_sizes, int n_in,
                              void* d_out, int out_size, void* d_ws, size_t ws_size,
                              hipStream_t stream)
{
    const float* Y      = (const float*)d_in[0];
    const float* X      = (const float*)d_in[1];
    const float* H      = (const float*)d_in[2];
    const float* C_w    = (const float*)d_in[4];
    const float* W_ih   = (const float*)d_in[5];
    const float* W_hh   = (const float*)d_in[6];
    const float* b_ih   = (const float*)d_in[7];
    const float* b_hh   = (const float*)d_in[8];
    const float* W_fc   = (const float*)d_in[9];
    const float* b_fc   = (const float*)d_in[10];
    const float* W_mean = (const float*)d_in[11];
    const float* b_mean = (const float*)d_in[12];
    const float* W_vars = (const float*)d_in[13];
    const float* b_vars = (const float*)d_in[14];
    float* out = (float*)d_out;

    float* h_out = (float*)d_ws;                       // 32.77 MB
    float* Ac = h_out + (size_t)N_ * T_ * HID_;
    float* Mc = Ac + NS_ * NO_;

    hipLaunchKernelGGL(setup_consts, dim3(1), dim3(64), 0, stream, H, C_w, Ac, Mc);
    hipLaunchKernelGGL(gru_kernel, dim3(N_), dim3(G3_), 0, stream,
                       Y, W_ih, W_hh, b_ih, b_hh, h_out);
    hipLaunchKernelGGL(init_out, dim3(1), dim3(1), 0, stream, out);
    hipLaunchKernelGGL(post_kernel, dim3((N_ * T_ + 255) / 256), dim3(256), 0, stream,
                       h_out, Y, X, W_fc, b_fc, W_mean, b_mean, W_vars, b_vars,
                       Ac, Mc, out);
}

// Round 7
// 553.052 us; speedup vs baseline: 1.2797x; 1.2797x over previous
//
#include <hip/hip_runtime.h>
#include <math.h>

// Problem constants (from reference)
#define N_    128
#define T_    1000
#define NS_   10
#define NO_   10
#define HID_  64
#define DENSE_ 32

typedef float v2f __attribute__((ext_vector_type(2)));
typedef float v4f __attribute__((ext_vector_type(4)));

// Barrier that waits only on LDS ops (global h_out stores are consumed by a
// later dispatch, never by another wave in-kernel -> no vmcnt drain).
#define LDS_BARRIER() asm volatile("s_waitcnt lgkmcnt(0)\n\ts_barrier" ::: "memory")

__device__ __forceinline__ float fast_sigmoid(float x) {
    return __builtin_amdgcn_rcpf(1.f + __expf(-x));   // NaN-safe
}
__device__ __forceinline__ float fast_tanh(float x) {
    float e = __expf(2.f * x);
    return 1.f - 2.f * __builtin_amdgcn_rcpf(e + 1.f); // NaN-safe
}

// ---------------------------------------------------------------------------
// Phase 0: precompute A = H^T inv(C_w) (NS x NO), M = A H (NS x NS)
// ---------------------------------------------------------------------------
__global__ void setup_consts(const float* __restrict__ H,
                             const float* __restrict__ C_w,
                             float* __restrict__ A,   // (NS,NO)
                             float* __restrict__ M)   // (NS,NS)
{
    if (threadIdx.x != 0 || blockIdx.x != 0) return;
    float W[NO_][2 * NO_];
    for (int i = 0; i < NO_; ++i) {
        for (int j = 0; j < NO_; ++j) {
            W[i][j] = C_w[i * NO_ + j];
            W[i][NO_ + j] = (i == j) ? 1.f : 0.f;
        }
    }
    for (int p = 0; p < NO_; ++p) {
        float ip = 1.f / W[p][p];
        for (int j = 0; j < 2 * NO_; ++j) W[p][j] *= ip;
        for (int i = 0; i < NO_; ++i) {
            if (i == p) continue;
            float f = W[i][p];
            for (int j = 0; j < 2 * NO_; ++j) W[i][j] -= f * W[p][j];
        }
    }
    float Aloc[NS_][NO_];
    for (int s = 0; s < NS_; ++s) {
        for (int o = 0; o < NO_; ++o) {
            float acc = 0.f;
            for (int p = 0; p < NO_; ++p) acc += H[p * NS_ + s] * W[p][NO_ + o];
            Aloc[s][o] = acc;
            A[s * NO_ + o] = acc;
        }
    }
    for (int s = 0; s < NS_; ++s) {
        for (int q = 0; q < NS_; ++q) {
            float acc = 0.f;
            for (int o = 0; o < NO_; ++o) acc += Aloc[s][o] * H[o * NS_ + q];
            M[s * NS_ + q] = acc;
        }
    }
}

// ---------------------------------------------------------------------------
// Phase 1: GRU scan. 6 waves per sample. Gate g gets 2 waves (j-halves);
// within a wave, lane pair (2m, 2m+1) shares row j = half*32+m: even lane
// holds W_hh[j][0..32), odd lane [32..64) -> 32-VGPR weight footprint per
// lane, pinned resident with asm VOLATILE (cannot be sunk into the loop;
// the r2..r6 remat-reload killer). Pair-combine via __shfl_xor(.,1) (DPP).
// Per step: own-half dot from private per-wave h copy (no barrier), publish
// {r,z,xn,hn} to gbuf, ONE LDS-only barrier, redundant combine on all waves.
// y prefetched 2 steps deep (covers ~900cy cold HBM at ~500cy steps).
// ---------------------------------------------------------------------------
__global__ __launch_bounds__(384, 1) void gru_kernel(
    const float* __restrict__ Y,     // (N,T,NO)
    const float* __restrict__ W_ih,  // (192,10)
    const float* __restrict__ W_hh,  // (192,64)
    const float* __restrict__ b_ih,
    const float* __restrict__ b_hh,
    float* __restrict__ h_out)       // (N*T,64)
{
    const int n    = blockIdx.x;
    const int tid  = threadIdx.x;
    const int w    = tid >> 6;            // wave 0..5
    const int g    = w >> 1;              // gate: 0=r, 1=z, 2=n
    const int half = w & 1;               // j-range half
    const int l    = tid & 63;
    const int j    = half * 32 + (l >> 1);// row within gate, 0..63
    const int kh   = l & 1;               // k-half: 0 -> k=0..31, 1 -> 32..63
    const int row  = g * HID_ + j;        // 0..191

    // --- weights: half a W_hh row (32 f = 16 v2f) + half a W_ih row (5 f) ---
    v2f whh[16];
    {
        const v2f* wp = (const v2f*)(W_hh + (size_t)row * HID_ + kh * 32);
#pragma unroll
        for (int k = 0; k < 16; ++k) whh[k] = wp[k];
    }
    float wih[5];
    {
        const float* ip = W_ih + (size_t)row * NO_ + kh * 5;
#pragma unroll
        for (int i = 0; i < 5; ++i) wih[i] = ip[i];
    }
    // VOLATILE pin: cannot be sunk/duplicated into the loop -> loads stay in
    // the preamble, values stay register-resident (demand ~70 VGPR, fits).
#pragma unroll
    for (int k = 0; k < 16; ++k) asm volatile("" : "+v"(whh[k]));
#pragma unroll
    for (int i = 0; i < 5; ++i) asm volatile("" : "+v"(wih[i]));

    const float bi = b_ih[row];
    const float bh = b_hh[row];
    const float cb = bi + bh;             // r,z combined bias

    __shared__ __align__(16) float h_copy[6][HID_];    // private per-wave h
    __shared__ __align__(16) float gbuf[2][HID_][4];   // j, {r,z,xn,hn}

    h_copy[w][l] = 0.f;                   // own copy: same-wave in-order
    float h_own = 0.f;                    // lane l's copy of h[l]

    const float* Yk  = Y + (size_t)n * T_ * NO_ + kh * 5;  // parity-split y
    float* hout = h_out + (size_t)n * T_ * HID_ + l;

    // depth-2 y prefetch: two rotating 5-float sets
    float ya[5], yb[5];
#pragma unroll
    for (int i = 0; i < 5; ++i) ya[i] = Yk[i];            // row 0
#pragma unroll
    for (int i = 0; i < 5; ++i) yb[i] = Yk[NO_ + i];      // row 1

    auto step = [&](int t, float (&yr)[5], int tload) {
        const int p = t & 1;

        // x-projection from registers (this lane's 5-wide half)
        float xpart = 0.f;
#pragma unroll
        for (int i = 0; i < 5; ++i) xpart += wih[i] * yr[i];

        // refill yr with row tload (used 2 steps from now)
        {
            const float* yp = Yk + (size_t)tload * NO_;
#pragma unroll
            for (int i = 0; i < 5; ++i) yr[i] = yp[i];
        }

        // h-projection: 8 b128 reads of own-wave h copy (2 addrs/wave: free)
        v2f a0 = {0.f, 0.f}, a1 = {0.f, 0.f};
        const v4f* hp = (const v4f*)(h_copy[w] + kh * 32);
#pragma unroll
        for (int k = 0; k < 8; ++k) {
            v4f h4 = hp[k];
            a0 += whh[2 * k]     * __builtin_shufflevector(h4, h4, 0, 1);
            a1 += whh[2 * k + 1] * __builtin_shufflevector(h4, h4, 2, 3);
        }
        v2f av = a0 + a1;
        const float hpart = av[0] + av[1];

        // pair-combine + nonlinearity + publish
        if (g < 2) {
            float s = xpart + hpart;
            s += __shfl_xor(s, 1);
            const float val = fast_sigmoid(s + cb);
            if (kh == 0) gbuf[p][j][g] = val;
        } else {
            const float xs = xpart + __shfl_xor(xpart, 1) + bi;
            const float hs = hpart + __shfl_xor(hpart, 1) + bh;
            if (kh == 0) { v2f xh = {xs, hs}; *(v2f*)&gbuf[p][j][2] = xh; }
        }
        LDS_BARRIER();

        // redundant combine on every wave; lane l owns h[l]
        const v4f gv = *(const v4f*)gbuf[p][l];   // {r,z,xn,hn} conflict-free
        const float nn = fast_tanh(gv[2] + gv[0] * gv[3]);
        const float h_new = nn + gv[1] * (h_own - nn);
        h_own = h_new;
        h_copy[w][l] = h_new;                     // own copy only
        if (w == 0) hout[t * HID_] = h_new;       // fire-and-forget
    };

    for (int t = 0; t < T_; t += 2) {
        const int t2 = (t + 2 < T_) ? t + 2 : T_ - 1;
        const int t3 = (t + 3 < T_) ? t + 3 : T_ - 1;
        step(t,     ya, t2);
        step(t + 1, yb, t3);
    }
}

// ---------------------------------------------------------------------------
// Phase 2a: init output with the constant term 0.5*NS*T*log(2*pi)
// ---------------------------------------------------------------------------
__global__ void init_out(float* __restrict__ out)
{
    if (threadIdx.x == 0 && blockIdx.x == 0) {
        out[0] = 0.5f * (float)NS_ * (float)T_ * logf(2.f * 3.14159265358979323846f);
    }
}

// ---------------------------------------------------------------------------
// Phase 2b: per-(n,t) dense head + information-form Kalman + log-pdf terms.
// ---------------------------------------------------------------------------
__global__ __launch_bounds__(256) void post_kernel(
    const float* __restrict__ h_out,  // (N*T,64)
    const float* __restrict__ Y,      // (N,T,NO)
    const float* __restrict__ X,      // (N,T,NS)
    const float* __restrict__ W_fc, const float* __restrict__ b_fc,
    const float* __restrict__ W_mean, const float* __restrict__ b_mean,
    const float* __restrict__ W_vars, const float* __restrict__ b_vars,
    const float* __restrict__ Ac,     // (NS,NO)
    const float* __restrict__ Mc,     // (NS,NS)
    float* __restrict__ out)
{
    __shared__ float sWfc[DENSE_][HID_];
    __shared__ float sWm[NS_][DENSE_];
    __shared__ float sWv[NS_][DENSE_];
    __shared__ float sA[NS_][NO_];
    __shared__ float sM[NS_][NS_];
    __shared__ float sbfc[DENSE_], sbm[NS_], sbv[NS_];
    __shared__ float wsum[4];

    for (int i = threadIdx.x; i < DENSE_ * HID_; i += blockDim.x)
        sWfc[i / HID_][i % HID_] = W_fc[i];
    for (int i = threadIdx.x; i < NS_ * DENSE_; i += blockDim.x) {
        sWm[i / DENSE_][i % DENSE_] = W_mean[i];
        sWv[i / DENSE_][i % DENSE_] = W_vars[i];
    }
    for (int i = threadIdx.x; i < NS_ * NO_; i += blockDim.x) sA[i / NO_][i % NO_] = Ac[i];
    for (int i = threadIdx.x; i < NS_ * NS_; i += blockDim.x) sM[i / NS_][i % NS_] = Mc[i];
    if (threadIdx.x < DENSE_) sbfc[threadIdx.x] = b_fc[threadIdx.x];
    if (threadIdx.x < NS_) { sbm[threadIdx.x] = b_mean[threadIdx.x]; sbv[threadIdx.x] = b_vars[threadIdx.x]; }
    __syncthreads();

    const int task = blockIdx.x * blockDim.x + threadIdx.x;
    float contrib = 0.f;
    if (task < N_ * T_) {
        float y[DENSE_];
#pragma unroll
        for (int d = 0; d < DENSE_; ++d) y[d] = sbfc[d];
        const float* hp = h_out + (size_t)task * HID_;
#pragma unroll
        for (int k = 0; k < HID_; k += 4) {
            float4 h4 = *(const float4*)(hp + k);
#pragma unroll
            for (int d = 0; d < DENSE_; ++d) {
                y[d] += sWfc[d][k + 0] * h4.x + sWfc[d][k + 1] * h4.y +
                        sWfc[d][k + 2] * h4.z + sWfc[d][k + 3] * h4.w;
            }
        }
#pragma unroll
        for (int d = 0; d < DENSE_; ++d) y[d] = fmaxf(y[d], 0.f);

        float mu[NS_], vinv[NS_];
#pragma unroll
        for (int s = 0; s < NS_; ++s) {
            float am = sbm[s], av = sbv[s];
#pragma unroll
            for (int d = 0; d < DENSE_; ++d) { am += sWm[s][d] * y[d]; av += sWv[s][d] * y[d]; }
            mu[s] = am;
            float sp = (av > 20.f) ? av : log1pf(__expf(av));  // softplus
            vinv[s] = 1.f / sp;
        }

        const float* yo = Y + (size_t)task * NO_;
        const float* xo = X + (size_t)task * NS_;
        float b[NS_];
#pragma unroll
        for (int s = 0; s < NS_; ++s) {
            float acc = vinv[s] * mu[s];
#pragma unroll
            for (int o = 0; o < NO_; ++o) acc += sA[s][o] * yo[o];
            b[s] = acc;
        }

        // L_inv = M + diag(v^-1), Cholesky
        float L[NS_][NS_];
#pragma unroll
        for (int i = 0; i < NS_; ++i)
#pragma unroll
            for (int jj = 0; jj <= i; ++jj)
                L[i][jj] = sM[i][jj] + ((i == jj) ? vinv[i] : 0.f);
        float ld = 0.f;
        float dinv[NS_];
#pragma unroll
        for (int jj = 0; jj < NS_; ++jj) {
            float s = L[jj][jj];
#pragma unroll
            for (int k = 0; k < jj; ++k) s -= L[jj][k] * L[jj][k];
            float d = sqrtf(s);
            ld += __logf(d);
            float di = 1.f / d;
            dinv[jj] = di;
            L[jj][jj] = d;
#pragma unroll
            for (int i = jj + 1; i < NS_; ++i) {
                float t2 = L[i][jj];
#pragma unroll
                for (int k = 0; k < jj; ++k) t2 -= L[i][k] * L[jj][k];
                L[i][jj] = t2 * di;
            }
        }
        ld *= 2.f;

        float w[NS_];
#pragma unroll
        for (int i = 0; i < NS_; ++i) {
            float s = b[i];
#pragma unroll
            for (int k = 0; k < i; ++k) s -= L[i][k] * w[k];
            w[i] = s * dinv[i];
        }
        float mpost[NS_];
#pragma unroll
        for (int ii = NS_ - 1; ii >= 0; --ii) {
            float s = w[ii];
#pragma unroll
            for (int k = ii + 1; k < NS_; ++k) s -= L[k][ii] * mpost[k];
            mpost[ii] = s * dinv[ii];
        }

        float diff[NS_];
#pragma unroll
        for (int s = 0; s < NS_; ++s) diff[s] = xo[s] - mpost[s];
        float quad = 0.f;
#pragma unroll
        for (int jj = 0; jj < NS_; ++jj) {
            float u = 0.f;
#pragma unroll
            for (int i = jj; i < NS_; ++i) u += L[i][jj] * diff[i];
            quad += u * u;
        }

        contrib = 0.5f * (ld - quad) * (1.0f / (float)N_);
    }

#pragma unroll
    for (int off = 32; off; off >>= 1) contrib += __shfl_down(contrib, off);
    const int wid = threadIdx.x >> 6;
    if ((threadIdx.x & 63) == 0) wsum[wid] = contrib;
    __syncthreads();
    if (threadIdx.x == 0) {
        float s = 0.f;
#pragma unroll
        for (int i = 0; i < 4; ++i) s += wsum[i];
        atomicAdd(out, s);
    }
}

// ---------------------------------------------------------------------------
extern "C" void kernel_launch(void* const* d_in, const int* in_sizes, int n_in,
                              void* d_out, int out_size, void* d_ws, size_t ws_size,
                              hipStream_t stream)
{
    const float* Y      = (const float*)d_in[0];
    const float* X      = (const float*)d_in[1];
    const float* H      = (const float*)d_in[2];
    const float* C_w    = (const float*)d_in[4];
    const float* W_ih   = (const float*)d_in[5];
    const float* W_hh   = (const float*)d_in[6];
    const float* b_ih   = (const float*)d_in[7];
    const float* b_hh   = (const float*)d_in[8];
    const float* W_fc   = (const float*)d_in[9];
    const float* b_fc   = (const float*)d_in[10];
    const float* W_mean = (const float*)d_in[11];
    const float* b_mean = (const float*)d_in[12];
    const float* W_vars = (const float*)d_in[13];
    const float* b_vars = (const float*)d_in[14];
    float* out = (float*)d_out;

    float* h_out = (float*)d_ws;                       // 32.77 MB
    float* Ac = h_out + (size_t)N_ * T_ * HID_;
    float* Mc = Ac + NS_ * NO_;

    hipLaunchKernelGGL(setup_consts, dim3(1), dim3(64), 0, stream, H, C_w, Ac, Mc);
    hipLaunchKernelGGL(gru_kernel, dim3(N_), dim3(384), 0, stream,
                       Y, W_ih, W_hh, b_ih, b_hh, h_out);
    hipLaunchKernelGGL(init_out, dim3(1), dim3(1), 0, stream, out);
    hipLaunchKernelGGL(post_kernel, dim3((N_ * T_ + 255) / 256), dim3(256), 0, stream,
                       h_out, Y, X, W_fc, b_fc, W_mean, b_mean, W_vars, b_vars,
                       Ac, Mc, out);
}

// Round 9
// 456.834 us; speedup vs baseline: 1.5492x; 1.2106x over previous
//
#include <hip/hip_runtime.h>
#include <math.h>

// Problem constants (from reference)
#define N_    128
#define T_    1000
#define NS_   10
#define NO_   10
#define HID_  64
#define DENSE_ 32

typedef float v2f __attribute__((ext_vector_type(2)));
typedef float v4f __attribute__((ext_vector_type(4)));
typedef _Float16 h2v __attribute__((ext_vector_type(2)));

// Barrier that waits only on LDS ops (global h_out stores are consumed by a
// later dispatch, never by another wave in-kernel -> no vmcnt drain).
#define LDS_BARRIER() asm volatile("s_waitcnt lgkmcnt(0)\n\ts_barrier" ::: "memory")

// f16 dot2: acc += a[0]*b[0] + a[1]*b[1]  (v_dot2_f32_f16)
#if __has_builtin(__builtin_amdgcn_fdot2)
#define FDOT2(acc, a, b) (acc) = __builtin_amdgcn_fdot2((a), (b), (acc), false)
#else
#define FDOT2(acc, a, b) asm("v_dot2_f32_f16 %0, %1, %2, %0" : "+v"(acc) : "v"(a), "v"(b))
#endif

// pack two f32 -> 2x f16 (v_cvt_pkrtz_f16_f32), bit-cast to our h2v type
__device__ __forceinline__ h2v pk_f16(float a, float b) {
    return __builtin_bit_cast(h2v, __builtin_amdgcn_cvt_pkrtz(a, b));
}

// lane^1 exchange via DPP quad_perm [1,0,3,2] — VALU speed, no LDS
__device__ __forceinline__ float dpp_xor1(float x) {
    int r = __builtin_amdgcn_update_dpp(0, __builtin_bit_cast(int, x),
                                        0xB1, 0xF, 0xF, true);
    return __builtin_bit_cast(float, r);
}

__device__ __forceinline__ float fast_sigmoid(float x) {
    return __builtin_amdgcn_rcpf(1.f + __expf(-x));   // NaN-safe
}
__device__ __forceinline__ float fast_tanh(float x) {
    float e = __expf(2.f * x);
    return 1.f - 2.f * __builtin_amdgcn_rcpf(e + 1.f); // NaN-safe
}

// ---------------------------------------------------------------------------
// Phase 0: precompute A = H^T inv(C_w) (NS x NO), M = A H (NS x NS); also
// initializes out[0] with the constant 0.5*NS*T*log(2*pi) term.
// ---------------------------------------------------------------------------
__global__ void setup_consts(const float* __restrict__ H,
                             const float* __restrict__ C_w,
                             float* __restrict__ A,   // (NS,NO)
                             float* __restrict__ M,   // (NS,NS)
                             float* __restrict__ out)
{
    if (threadIdx.x != 0 || blockIdx.x != 0) return;
    out[0] = 0.5f * (float)NS_ * (float)T_ * logf(2.f * 3.14159265358979323846f);
    float W[NO_][2 * NO_];
    for (int i = 0; i < NO_; ++i) {
        for (int j = 0; j < NO_; ++j) {
            W[i][j] = C_w[i * NO_ + j];
            W[i][NO_ + j] = (i == j) ? 1.f : 0.f;
        }
    }
    for (int p = 0; p < NO_; ++p) {
        float ip = 1.f / W[p][p];
        for (int j = 0; j < 2 * NO_; ++j) W[p][j] *= ip;
        for (int i = 0; i < NO_; ++i) {
            if (i == p) continue;
            float f = W[i][p];
            for (int j = 0; j < 2 * NO_; ++j) W[i][j] -= f * W[p][j];
        }
    }
    float Aloc[NS_][NO_];
    for (int s = 0; s < NS_; ++s) {
        for (int o = 0; o < NO_; ++o) {
            float acc = 0.f;
            for (int p = 0; p < NO_; ++p) acc += H[p * NS_ + s] * W[p][NO_ + o];
            Aloc[s][o] = acc;
            A[s * NO_ + o] = acc;
        }
    }
    for (int s = 0; s < NS_; ++s) {
        for (int q = 0; q < NS_; ++q) {
            float acc = 0.f;
            for (int o = 0; o < NO_; ++o) acc += Aloc[s][o] * H[o * NS_ + q];
            M[s * NS_ + q] = acc;
        }
    }
}

// ---------------------------------------------------------------------------
// Phase 1: GRU scan. 2 waves per sample; lane pair (2m,2m+1) owns hidden unit
// j (wave w: j = w*32+m) for ALL THREE gates, split across K-halves (kh=l&1).
// Weights: 3x16 f16-pairs (~24 VGPR) + 3x5 f32 W_ih, pinned volatile (r7
// proved the pin). Per step: x-proj f32 (registers) | one uniform LDS read of
// prev h (f16, 4xb128) | 48x v_dot2_f32_f16 | pair-combine via DPP quad-perm
// (no LDS) | sigmoid/tanh lane-local | even lane publishes h (f16 ->
// double-buffered hbuf, f32 -> h_out fire-and-forget) | ONE 2-wave LDS-only
// barrier. No gate exchange: gates are lane-local by construction.
// ---------------------------------------------------------------------------
__global__ __launch_bounds__(128, 1) void gru_kernel(
    const float* __restrict__ Y,     // (N,T,NO)
    const float* __restrict__ W_ih,  // (192,10)
    const float* __restrict__ W_hh,  // (192,64)
    const float* __restrict__ b_ih,
    const float* __restrict__ b_hh,
    float* __restrict__ h_out)       // (N*T,64)
{
    const int n   = blockIdx.x;
    const int tid = threadIdx.x;     // 0..127
    const int w   = tid >> 6;        // wave 0,1
    const int l   = tid & 63;
    const int j   = w * 32 + (l >> 1);   // hidden unit 0..63
    const int kh  = l & 1;               // K half: 0 -> k 0..31, 1 -> 32..63

    // --- weights: 3 gate rows of W_hh (K-half, f16 pairs) + W_ih (f32) ---
    h2v whh[3][16];
#pragma unroll
    for (int g = 0; g < 3; ++g) {
        const v4f* wp = (const v4f*)(W_hh + (size_t)(g * HID_ + j) * HID_ + kh * 32);
#pragma unroll
        for (int q = 0; q < 8; ++q) {
            v4f t = wp[q];
            whh[g][2 * q]     = pk_f16(t.x, t.y);
            whh[g][2 * q + 1] = pk_f16(t.z, t.w);
        }
    }
    float wih[3][5];
#pragma unroll
    for (int g = 0; g < 3; ++g) {
        const float* ip = W_ih + (size_t)(g * HID_ + j) * NO_ + kh * 5;
#pragma unroll
        for (int i = 0; i < 5; ++i) wih[g][i] = ip[i];
    }
    // VOLATILE pin: cannot be sunk into the loop -> values stay resident.
#pragma unroll
    for (int g = 0; g < 3; ++g) {
#pragma unroll
        for (int k = 0; k < 16; ++k) asm volatile("" : "+v"(whh[g][k]));
#pragma unroll
        for (int i = 0; i < 5; ++i) asm volatile("" : "+v"(wih[g][i]));
    }

    const float bR  = b_ih[j] + b_hh[j];
    const float bZ  = b_ih[HID_ + j] + b_hh[HID_ + j];
    const float bNx = b_ih[2 * HID_ + j];
    const float bNh = b_hh[2 * HID_ + j];

    // double-buffered f16 hidden state (state t lives in hbuf[t&1])
    __shared__ __align__(16) _Float16 hbuf[2][HID_];
    if (tid < HID_) hbuf[1][tid] = (_Float16)0.f;   // state "t=-1"
    float h_own = 0.f;
    LDS_BARRIER();

    const float* Yk = Y + (size_t)n * T_ * NO_ + kh * 5;
    float* hout = h_out + (size_t)n * T_ * HID_ + j;

    // depth-2 y prefetch
    float ya[5], yb[5];
#pragma unroll
    for (int i = 0; i < 5; ++i) ya[i] = Yk[i];
#pragma unroll
    for (int i = 0; i < 5; ++i) yb[i] = Yk[NO_ + i];

    auto step = [&](int t, float (&yr)[5], int tload) {
        // x-projection (f32, registers; off critical path)
        float xr = 0.f, xz = 0.f, xn = 0.f;
#pragma unroll
        for (int i = 0; i < 5; ++i) {
            xr += wih[0][i] * yr[i];
            xz += wih[1][i] * yr[i];
            xn += wih[2][i] * yr[i];
        }
        // refill yr (used 2 steps from now)
        {
            const float* yp = Yk + (size_t)tload * NO_;
#pragma unroll
            for (int i = 0; i < 5; ++i) yr[i] = yp[i];
        }
        // h-projection: uniform b128 reads of prev state (own K-half)
        float ar = 0.f, az = 0.f, an = 0.f;
        const uint4* hp = (const uint4*)(&hbuf[1 - (t & 1)][kh * 32]);
#pragma unroll
        for (int q = 0; q < 4; ++q) {
            uint4 hq = hp[q];
            h2v h0 = __builtin_bit_cast(h2v, hq.x);
            h2v h1 = __builtin_bit_cast(h2v, hq.y);
            h2v h2 = __builtin_bit_cast(h2v, hq.z);
            h2v h3 = __builtin_bit_cast(h2v, hq.w);
            FDOT2(ar, whh[0][4*q+0], h0); FDOT2(az, whh[1][4*q+0], h0); FDOT2(an, whh[2][4*q+0], h0);
            FDOT2(ar, whh[0][4*q+1], h1); FDOT2(az, whh[1][4*q+1], h1); FDOT2(an, whh[2][4*q+1], h1);
            FDOT2(ar, whh[0][4*q+2], h2); FDOT2(az, whh[1][4*q+2], h2); FDOT2(an, whh[2][4*q+2], h2);
            FDOT2(ar, whh[0][4*q+3], h3); FDOT2(az, whh[1][4*q+3], h3); FDOT2(an, whh[2][4*q+3], h3);
        }
        // pair-combine via DPP (lane^1), both lanes end with full sums
        float sr = xr + ar;  sr += dpp_xor1(sr);
        float sz = xz + az;  sz += dpp_xor1(sz);
        float sx = xn;       sx += dpp_xor1(sx);
        float sh = an;       sh += dpp_xor1(sh);
        const float r  = fast_sigmoid(sr + bR);
        const float z  = fast_sigmoid(sz + bZ);
        const float nn = fast_tanh(sx + bNx + r * (sh + bNh));
        const float h_new = nn + z * (h_own - nn);
        h_own = h_new;
        if (kh == 0) {
            hbuf[t & 1][j] = (_Float16)h_new;   // next-step state (f16)
            hout[t * HID_] = h_new;             // fire-and-forget (f32)
        }
        LDS_BARRIER();
    };

    for (int t = 0; t < T_; t += 2) {
        const int t2 = (t + 2 < T_) ? t + 2 : T_ - 1;
        const int t3 = (t + 3 < T_) ? t + 3 : T_ - 1;
        step(t,     ya, t2);
        step(t + 1, yb, t3);
    }
}

// ---------------------------------------------------------------------------
// Phase 2: per-(n,t) dense head + information-form Kalman + log-pdf terms.
// ---------------------------------------------------------------------------
__global__ __launch_bounds__(256) void post_kernel(
    const float* __restrict__ h_out,  // (N*T,64)
    const float* __restrict__ Y,      // (N,T,NO)
    const float* __restrict__ X,      // (N,T,NS)
    const float* __restrict__ W_fc, const float* __restrict__ b_fc,
    const float* __restrict__ W_mean, const float* __restrict__ b_mean,
    const float* __restrict__ W_vars, const float* __restrict__ b_vars,
    const float* __restrict__ Ac,     // (NS,NO)
    const float* __restrict__ Mc,     // (NS,NS)
    float* __restrict__ out)
{
    __shared__ float sWfc[DENSE_][HID_];
    __shared__ float sWm[NS_][DENSE_];
    __shared__ float sWv[NS_][DENSE_];
    __shared__ float sA[NS_][NO_];
    __shared__ float sM[NS_][NS_];
    __shared__ float sbfc[DENSE_], sbm[NS_], sbv[NS_];
    __shared__ float wsum[4];

    for (int i = threadIdx.x; i < DENSE_ * HID_; i += blockDim.x)
        sWfc[i / HID_][i % HID_] = W_fc[i];
    for (int i = threadIdx.x; i < NS_ * DENSE_; i += blockDim.x) {
        sWm[i / DENSE_][i % DENSE_] = W_mean[i];
        sWv[i / DENSE_][i % DENSE_] = W_vars[i];
    }
    for (int i = threadIdx.x; i < NS_ * NO_; i += blockDim.x) sA[i / NO_][i % NO_] = Ac[i];
    for (int i = threadIdx.x; i < NS_ * NS_; i += blockDim.x) sM[i / NS_][i % NS_] = Mc[i];
    if (threadIdx.x < DENSE_) sbfc[threadIdx.x] = b_fc[threadIdx.x];
    if (threadIdx.x < NS_) { sbm[threadIdx.x] = b_mean[threadIdx.x]; sbv[threadIdx.x] = b_vars[threadIdx.x]; }
    __syncthreads();

    const int task = blockIdx.x * blockDim.x + threadIdx.x;
    float contrib = 0.f;
    if (task < N_ * T_) {
        float y[DENSE_];
#pragma unroll
        for (int d = 0; d < DENSE_; ++d) y[d] = sbfc[d];
        const float* hp = h_out + (size_t)task * HID_;
#pragma unroll
        for (int k = 0; k < HID_; k += 4) {
            float4 h4 = *(const float4*)(hp + k);
#pragma unroll
            for (int d = 0; d < DENSE_; ++d) {
                y[d] += sWfc[d][k + 0] * h4.x + sWfc[d][k + 1] * h4.y +
                        sWfc[d][k + 2] * h4.z + sWfc[d][k + 3] * h4.w;
            }
        }
#pragma unroll
        for (int d = 0; d < DENSE_; ++d) y[d] = fmaxf(y[d], 0.f);

        float mu[NS_], vinv[NS_];
#pragma unroll
        for (int s = 0; s < NS_; ++s) {
            float am = sbm[s], av = sbv[s];
#pragma unroll
            for (int d = 0; d < DENSE_; ++d) { am += sWm[s][d] * y[d]; av += sWv[s][d] * y[d]; }
            mu[s] = am;
            float sp = (av > 20.f) ? av : log1pf(__expf(av));  // softplus
            vinv[s] = 1.f / sp;
        }

        const float* yo = Y + (size_t)task * NO_;
        const float* xo = X + (size_t)task * NS_;
        float b[NS_];
#pragma unroll
        for (int s = 0; s < NS_; ++s) {
            float acc = vinv[s] * mu[s];
#pragma unroll
            for (int o = 0; o < NO_; ++o) acc += sA[s][o] * yo[o];
            b[s] = acc;
        }

        // L_inv = M + diag(v^-1), Cholesky
        float L[NS_][NS_];
#pragma unroll
        for (int i = 0; i < NS_; ++i)
#pragma unroll
            for (int jj = 0; jj <= i; ++jj)
                L[i][jj] = sM[i][jj] + ((i == jj) ? vinv[i] : 0.f);
        float ld = 0.f;
        float dinv[NS_];
#pragma unroll
        for (int jj = 0; jj < NS_; ++jj) {
            float s = L[jj][jj];
#pragma unroll
            for (int k = 0; k < jj; ++k) s -= L[jj][k] * L[jj][k];
            float d = sqrtf(s);
            ld += __logf(d);
            float di = 1.f / d;
            dinv[jj] = di;
            L[jj][jj] = d;
#pragma unroll
            for (int i = jj + 1; i < NS_; ++i) {
                float t2 = L[i][jj];
#pragma unroll
                for (int k = 0; k < jj; ++k) t2 -= L[i][k] * L[jj][k];
                L[i][jj] = t2 * di;
            }
        }
        ld *= 2.f;

        float w[NS_];
#pragma unroll
        for (int i = 0; i < NS_; ++i) {
            float s = b[i];
#pragma unroll
            for (int k = 0; k < i; ++k) s -= L[i][k] * w[k];
            w[i] = s * dinv[i];
        }
        float mpost[NS_];
#pragma unroll
        for (int ii = NS_ - 1; ii >= 0; --ii) {
            float s = w[ii];
#pragma unroll
            for (int k = ii + 1; k < NS_; ++k) s -= L[k][ii] * mpost[k];
            mpost[ii] = s * dinv[ii];
        }

        float diff[NS_];
#pragma unroll
        for (int s = 0; s < NS_; ++s) diff[s] = xo[s] - mpost[s];
        float quad = 0.f;
#pragma unroll
        for (int jj = 0; jj < NS_; ++jj) {
            float u = 0.f;
#pragma unroll
            for (int i = jj; i < NS_; ++i) u += L[i][jj] * diff[i];
            quad += u * u;
        }

        contrib = 0.5f * (ld - quad) * (1.0f / (float)N_);
    }

#pragma unroll
    for (int off = 32; off; off >>= 1) contrib += __shfl_down(contrib, off);
    const int wid = threadIdx.x >> 6;
    if ((threadIdx.x & 63) == 0) wsum[wid] = contrib;
    __syncthreads();
    if (threadIdx.x == 0) {
        float s = 0.f;
#pragma unroll
        for (int i = 0; i < 4; ++i) s += wsum[i];
        atomicAdd(out, s);
    }
}

// ---------------------------------------------------------------------------
extern "C" void kernel_launch(void* const* d_in, const int* in_sizes, int n_in,
                              void* d_out, int out_size, void* d_ws, size_t ws_size,
                              hipStream_t stream)
{
    const float* Y      = (const float*)d_in[0];
    const float* X      = (const float*)d_in[1];
    const float* H      = (const float*)d_in[2];
    const float* C_w    = (const float*)d_in[4];
    const float* W_ih   = (const float*)d_in[5];
    const float* W_hh   = (const float*)d_in[6];
    const float* b_ih   = (const float*)d_in[7];
    const float* b_hh   = (const float*)d_in[8];
    const float* W_fc   = (const float*)d_in[9];
    const float* b_fc   = (const float*)d_in[10];
    const float* W_mean = (const float*)d_in[11];
    const float* b_mean = (const float*)d_in[12];
    const float* W_vars = (const float*)d_in[13];
    const float* b_vars = (const float*)d_in[14];
    float* out = (float*)d_out;

    float* h_out = (float*)d_ws;                       // 32.77 MB
    float* Ac = h_out + (size_t)N_ * T_ * HID_;
    float* Mc = Ac + NS_ * NO_;

    hipLaunchKernelGGL(setup_consts, dim3(1), dim3(64), 0, stream, H, C_w, Ac, Mc, out);
    hipLaunchKernelGGL(gru_kernel, dim3(N_), dim3(128), 0, stream,
                       Y, W_ih, W_hh, b_ih, b_hh, h_out);
    hipLaunchKernelGGL(post_kernel, dim3((N_ * T_ + 255) / 256), dim3(256), 0, stream,
                       h_out, Y, X, W_fc, b_fc, W_mean, b_mean, W_vars, b_vars,
                       Ac, Mc, out);
}